// Round 3
// baseline (333.260 us; speedup 1.0000x reference)
//
#include <hip/hip_runtime.h>

// Multi-Scale Deformable Attention, split: gather kernel + in-place output GEMM.
// BS=2, NQ=32768, C=128, NH=1, NL=2, NP=8, NV=40960
// level0 = 128x256 (start 0), level1 = 64x128 (start 32768)

#define QB 32  // queries per block (gather kernel)

// 7 blocks/CU (LDS 22.5KB*7 = 157.5KB <= 160KB); VGPR must stay <= 73.
__global__ __launch_bounds__(256, 7) void msda_gather_kernel(
    const float* __restrict__ query,
    const float* __restrict__ value,
    const float* __restrict__ qloc,
    const float* __restrict__ Woff,
    const float* __restrict__ boff,
    const float* __restrict__ Wattn,
    const float* __restrict__ battn,
    float* __restrict__ acc_out)   // d_out used as acc buffer [65536 x 128]
{
    // 16 KB region: q_tile during logits, then (wo_w, wo_o) sample tables
    __shared__ __align__(16) char smem_u[QB * 128 * 4];
    __shared__ float coords[QB * 32];   // 4 KB: [q][p*2 + d]
    __shared__ float aws[QB * 16];      // 2 KB: [q][p]

    float*  q_tile = (float*)smem_u;
    float4* wo_w   = (float4*)smem_u;                  // 512 entries, 8 KB
    int4*   wo_o   = (int4*)(smem_u + QB * 16 * 16);   // 512 entries, 8 KB

    const int tid = threadIdx.x;
    const int r0  = blockIdx.x * QB;    // flat row = b*32768 + q

    // ---- phase 1: stage 32x128 query tile (1024 float4, coalesced) ----
    {
        const float4* src = (const float4*)query + (size_t)r0 * 32;
        float4* dst = (float4*)q_tile;
        #pragma unroll
        for (int i = 0; i < 4; ++i)
            dst[tid + i * 256] = src[tid + i * 256];
    }
    __syncthreads();

    // ---- phase 2: offset logits -> sample coordinates ----
    {
        const int jo = tid & 31;          // offset column 0..31
        const int qb = (tid >> 5) * 4;    // 8 groups x 4 queries
        float s[4] = {0.f, 0.f, 0.f, 0.f};
        for (int c4 = 0; c4 < 32; ++c4) {
            const float w0 = Woff[(c4 * 4 + 0) * 32 + jo];
            const float w1 = Woff[(c4 * 4 + 1) * 32 + jo];
            const float w2 = Woff[(c4 * 4 + 2) * 32 + jo];
            const float w3 = Woff[(c4 * 4 + 3) * 32 + jo];
            #pragma unroll
            for (int k = 0; k < 4; ++k) {
                const float4 q4 = *(const float4*)&q_tile[(qb + k) * 128 + c4 * 4];
                s[k] += q4.x * w0 + q4.y * w1 + q4.z * w2 + q4.w * w3;
            }
        }
        const int l = jo >> 4;
        const int d = jo & 1;
        const float scale = (d == 0) ? (l == 0 ? 256.f : 128.f)
                                     : (l == 0 ? 128.f : 64.f);
        const float bo = boff[jo];
        #pragma unroll
        for (int k = 0; k < 4; ++k) {
            const int row = r0 + qb + k;
            const float ql = qloc[row * 4 + l * 2 + d];
            coords[(qb + k) * 32 + jo] = ql * scale + (s[k] + bo) - 0.5f;
        }
    }

    // ---- phase 3: attention logits ----
    {
        const int ja = tid & 15;
        const int qb = (tid >> 4) * 2;    // 16 groups x 2 queries
        float s[2] = {0.f, 0.f};
        for (int c4 = 0; c4 < 32; ++c4) {
            const float w0 = Wattn[(c4 * 4 + 0) * 16 + ja];
            const float w1 = Wattn[(c4 * 4 + 1) * 16 + ja];
            const float w2 = Wattn[(c4 * 4 + 2) * 16 + ja];
            const float w3 = Wattn[(c4 * 4 + 3) * 16 + ja];
            #pragma unroll
            for (int k = 0; k < 2; ++k) {
                const float4 q4 = *(const float4*)&q_tile[(qb + k) * 128 + c4 * 4];
                s[k] += q4.x * w0 + q4.y * w1 + q4.z * w2 + q4.w * w3;
            }
        }
        const float ba = battn[ja];
        #pragma unroll
        for (int k = 0; k < 2; ++k)
            aws[(qb + k) * 16 + ja] = s[k] + ba;
    }
    __syncthreads();   // coords + attn logits ready; q_tile reads complete

    // ---- softmax over 16 weights per query ----
    if (tid < QB) {
        float* a = &aws[tid * 16];
        float m = a[0];
        #pragma unroll
        for (int j = 1; j < 16; ++j) m = fmaxf(m, a[j]);
        float sum = 0.f;
        #pragma unroll
        for (int j = 0; j < 16; ++j) {
            const float e = __expf(a[j] - m);
            a[j] = e;
            sum += e;
        }
        const float r = 1.f / sum;
        #pragma unroll
        for (int j = 0; j < 16; ++j) a[j] *= r;
    }
    __syncthreads();

    // ---- build per-(q,point) sample table: folded weights + corner offsets ----
    #pragma unroll
    for (int e = tid; e < QB * 16; e += 256) {
        const int q = e >> 4;
        const int p = e & 15;
        const int l = p >> 3;
        const int H = l ? 64 : 128;
        const int W = l ? 128 : 256;
        const int S = l ? 32768 : 0;
        const float x   = coords[q * 32 + p * 2 + 0];
        const float y   = coords[q * 32 + p * 2 + 1];
        const float wgt = aws[q * 16 + p];
        const float xf = floorf(x), yf = floorf(y);
        const float lx = x - xf, ly = y - yf;
        const int x0 = (int)xf, y0 = (int)yf;
        const int x1 = x0 + 1, y1 = y0 + 1;
        const float hx = 1.f - lx, hy = 1.f - ly;
        float w00 = wgt * hx * hy;
        float w10 = wgt * lx * hy;
        float w01 = wgt * hx * ly;
        float w11 = wgt * lx * ly;
        if (x0 < 0 || x0 >= W) { w00 = 0.f; w01 = 0.f; }
        if (x1 < 0 || x1 >= W) { w10 = 0.f; w11 = 0.f; }
        if (y0 < 0 || y0 >= H) { w00 = 0.f; w10 = 0.f; }
        if (y1 < 0 || y1 >= H) { w01 = 0.f; w11 = 0.f; }
        const int cx0 = min(max(x0, 0), W - 1);
        const int cx1 = min(max(x1, 0), W - 1);
        const int cy0 = min(max(y0, 0), H - 1);
        const int cy1 = min(max(y1, 0), H - 1);
        wo_w[e] = make_float4(w00, w10, w01, w11);
        wo_o[e] = make_int4((S + cy0 * W + cx0) * 32,
                            (S + cy0 * W + cx1) * 32,
                            (S + cy1 * W + cx0) * 32,
                            (S + cy1 * W + cx1) * 32);
    }
    __syncthreads();

    // ---- gather: half-wave (32 lanes = 32 channel-groups) per query ----
    {
        const int grp  = tid >> 5;   // 0..7
        const int lane = tid & 31;   // channels lane*4 .. lane*4+3
        const float4* vb = (const float4*)value
                         + (size_t)(blockIdx.x >> 10) * (40960 * 32);
        float4* og = (float4*)acc_out;
        #pragma unroll 1
        for (int i = 0; i < QB / 8; ++i) {
            const int q = i * 8 + grp;
            float ax = 0.f, ay = 0.f, az = 0.f, aw4 = 0.f;
            #pragma unroll 1
            for (int p0 = 0; p0 < 16; p0 += 4) {
                #pragma unroll
                for (int pi = 0; pi < 4; ++pi) {
                    const int e = q * 16 + p0 + pi;
                    const float4 w = wo_w[e];
                    const int4  o = wo_o[e];
                    const float4 v00 = vb[o.x + lane];
                    const float4 v10 = vb[o.y + lane];
                    const float4 v01 = vb[o.z + lane];
                    const float4 v11 = vb[o.w + lane];
                    ax  += w.x * v00.x + w.y * v10.x + w.z * v01.x + w.w * v11.x;
                    ay  += w.x * v00.y + w.y * v10.y + w.z * v01.y + w.w * v11.y;
                    az  += w.x * v00.z + w.y * v10.z + w.z * v01.z + w.w * v11.z;
                    aw4 += w.x * v00.w + w.y * v10.w + w.z * v01.w + w.w * v11.w;
                }
            }
            og[(size_t)(r0 + q) * 32 + lane] = make_float4(ax, ay, az, aw4);
        }
    }
}

// In-place output GEMM: out[r,:] = acc[r,:] @ Wout + bout.
// 128 rows/block; W staged in LDS in two 64-ci halves (no redundant global W
// reads). In-place safe: each block reads only rows it later writes, and all
// reads precede all writes.
#define GR 128

__global__ __launch_bounds__(256, 2) void msda_out_gemm_kernel(
    const float* __restrict__ Wout,
    const float* __restrict__ bout,
    float* __restrict__ out)
{
    __shared__ __align__(16) float a_tile[GR * 68];    // 34 KB (pad 64->68, 16B-aligned rows)
    __shared__ __align__(16) float w_tile[64 * 128];   // 32 KB
    const int tid  = threadIdx.x;
    const int r0   = blockIdx.x * GR;
    const int trow = tid >> 4;    // 0..15 -> rows trow + 16*k (interleaved)
    const int tcol = tid & 15;    // cols tcol*8 .. tcol*8+7

    float4 o[8][2];
    #pragma unroll
    for (int k = 0; k < 8; ++k) {
        o[k][0] = make_float4(0.f, 0.f, 0.f, 0.f);
        o[k][1] = make_float4(0.f, 0.f, 0.f, 0.f);
    }

    #pragma unroll 1
    for (int h = 0; h < 2; ++h) {
        // stage a-tile: 128 rows x 16 float4 (ci = h*64 .. h*64+63)
        {
            const float4* src = (const float4*)out;
            #pragma unroll
            for (int i = 0; i < 8; ++i) {
                const int t  = tid + i * 256;      // 0..2047
                const int r  = t >> 4;
                const int c4 = t & 15;
                const float4 v = src[(size_t)(r0 + r) * 32 + h * 16 + c4];
                *(float4*)&a_tile[r * 68 + c4 * 4] = v;
            }
            // stage W rows h*64 .. h*64+63 (2048 float4, coalesced)
            const float4* ws = (const float4*)Wout + (size_t)h * 64 * 32;
            float4* wd = (float4*)w_tile;
            #pragma unroll
            for (int i = 0; i < 8; ++i)
                wd[tid + i * 256] = ws[tid + i * 256];
        }
        __syncthreads();

        #pragma unroll 1
        for (int c4 = 0; c4 < 16; ++c4) {
            float4 a4[8];
            #pragma unroll
            for (int k = 0; k < 8; ++k)
                a4[k] = *(const float4*)&a_tile[(trow + 16 * k) * 68 + c4 * 4];
            #pragma unroll
            for (int j = 0; j < 4; ++j) {
                const int ci = c4 * 4 + j;
                const float4 w0 = *(const float4*)&w_tile[ci * 128 + tcol * 8];
                const float4 w1 = *(const float4*)&w_tile[ci * 128 + tcol * 8 + 4];
                #pragma unroll
                for (int k = 0; k < 8; ++k) {
                    const float a = (j == 0) ? a4[k].x : (j == 1) ? a4[k].y
                                  : (j == 2) ? a4[k].z : a4[k].w;
                    o[k][0].x += a * w0.x; o[k][0].y += a * w0.y;
                    o[k][0].z += a * w0.z; o[k][0].w += a * w0.w;
                    o[k][1].x += a * w1.x; o[k][1].y += a * w1.y;
                    o[k][1].z += a * w1.z; o[k][1].w += a * w1.w;
                }
            }
        }
        __syncthreads();
    }

    const float4 b0 = ((const float4*)bout)[tcol * 2];
    const float4 b1 = ((const float4*)bout)[tcol * 2 + 1];
    float4* og = (float4*)out;
    #pragma unroll
    for (int k = 0; k < 8; ++k) {
        const size_t row = (size_t)(r0 + trow + 16 * k);
        float4 v0 = o[k][0], v1 = o[k][1];
        v0.x += b0.x; v0.y += b0.y; v0.z += b0.z; v0.w += b0.w;
        v1.x += b1.x; v1.y += b1.y; v1.z += b1.z; v1.w += b1.w;
        og[row * 32 + tcol * 2]     = v0;
        og[row * 32 + tcol * 2 + 1] = v1;
    }
}

extern "C" void kernel_launch(void* const* d_in, const int* in_sizes, int n_in,
                              void* d_out, int out_size, void* d_ws, size_t ws_size,
                              hipStream_t stream) {
    const float* query = (const float*)d_in[0];
    const float* value = (const float*)d_in[1];
    const float* qloc  = (const float*)d_in[2];
    // d_in[3] spatial_shapes, d_in[4] level_start_index: compile-time constants
    const float* Woff  = (const float*)d_in[5];
    const float* boff  = (const float*)d_in[6];
    const float* Wattn = (const float*)d_in[7];
    const float* battn = (const float*)d_in[8];
    const float* Wout  = (const float*)d_in[9];
    const float* bout  = (const float*)d_in[10];
    float* out = (float*)d_out;

    hipLaunchKernelGGL(msda_gather_kernel, dim3(65536 / QB), dim3(256), 0, stream,
                       query, value, qloc, Woff, boff, Wattn, battn, out);
    hipLaunchKernelGGL(msda_out_gemm_kernel, dim3(65536 / GR), dim3(256), 0, stream,
                       Wout, bout, out);
}

// Round 4
// 274.770 us; speedup vs baseline: 1.2129x; 1.2129x over previous
//
#include <hip/hip_runtime.h>

// Multi-Scale Deformable Attention, split: gather kernel + in-place output GEMM.
// BS=2, NQ=32768, C=128, NH=1, NL=2, NP=8, NV=40960
// level0 = 128x256 (start 0), level1 = 64x128 (start 32768)

#define QB 32  // queries per block (gather kernel)

// 4 blocks/CU target: VGPR cap 128 — we deliberately use ~115 for deep
// load batching (R3 showed VGPR-starved waves lose to fewer, deeper waves).
__global__ __launch_bounds__(256, 4) void msda_gather_kernel(
    const float* __restrict__ query,
    const float* __restrict__ value,
    const float* __restrict__ qloc,
    const float* __restrict__ Woff,
    const float* __restrict__ boff,
    const float* __restrict__ Wattn,
    const float* __restrict__ battn,
    float* __restrict__ acc_out)   // d_out used as acc buffer [65536 x 128]
{
    // 16 KB region: q_tile during logits, then (wo_w, wo_o) sample tables
    __shared__ __align__(16) char smem_u[QB * 128 * 4];
    __shared__ float coords[QB * 32];   // 4 KB: [q][p*2 + d]
    __shared__ float aws[QB * 16];      // 2 KB: [q][p]

    float*  q_tile = (float*)smem_u;
    float4* wo_w   = (float4*)smem_u;                  // 512 entries, 8 KB
    int4*   wo_o   = (int4*)(smem_u + QB * 16 * 16);   // 512 entries, 8 KB

    const int tid = threadIdx.x;
    const int r0  = blockIdx.x * QB;    // flat row = b*32768 + q

    // ---- phase 1: stage 32x128 query tile (1024 float4, coalesced) ----
    {
        const float4* src = (const float4*)query + (size_t)r0 * 32;
        float4* dst = (float4*)q_tile;
        #pragma unroll
        for (int i = 0; i < 4; ++i)
            dst[tid + i * 256] = src[tid + i * 256];
    }
    __syncthreads();

    // ---- phase 2: offset logits -> sample coordinates ----
    {
        const int jo = tid & 31;          // offset column 0..31
        const int qb = (tid >> 5) * 4;    // 8 groups x 4 queries
        float s[4] = {0.f, 0.f, 0.f, 0.f};
        for (int c4 = 0; c4 < 32; ++c4) {
            const float w0 = Woff[(c4 * 4 + 0) * 32 + jo];
            const float w1 = Woff[(c4 * 4 + 1) * 32 + jo];
            const float w2 = Woff[(c4 * 4 + 2) * 32 + jo];
            const float w3 = Woff[(c4 * 4 + 3) * 32 + jo];
            #pragma unroll
            for (int k = 0; k < 4; ++k) {
                const float4 q4 = *(const float4*)&q_tile[(qb + k) * 128 + c4 * 4];
                s[k] += q4.x * w0 + q4.y * w1 + q4.z * w2 + q4.w * w3;
            }
        }
        const int l = jo >> 4;
        const int d = jo & 1;
        const float scale = (d == 0) ? (l == 0 ? 256.f : 128.f)
                                     : (l == 0 ? 128.f : 64.f);
        const float bo = boff[jo];
        #pragma unroll
        for (int k = 0; k < 4; ++k) {
            const int row = r0 + qb + k;
            const float ql = qloc[row * 4 + l * 2 + d];
            coords[(qb + k) * 32 + jo] = ql * scale + (s[k] + bo) - 0.5f;
        }
    }

    // ---- phase 3: attention logits ----
    {
        const int ja = tid & 15;
        const int qb = (tid >> 4) * 2;    // 16 groups x 2 queries
        float s[2] = {0.f, 0.f};
        for (int c4 = 0; c4 < 32; ++c4) {
            const float w0 = Wattn[(c4 * 4 + 0) * 16 + ja];
            const float w1 = Wattn[(c4 * 4 + 1) * 16 + ja];
            const float w2 = Wattn[(c4 * 4 + 2) * 16 + ja];
            const float w3 = Wattn[(c4 * 4 + 3) * 16 + ja];
            #pragma unroll
            for (int k = 0; k < 2; ++k) {
                const float4 q4 = *(const float4*)&q_tile[(qb + k) * 128 + c4 * 4];
                s[k] += q4.x * w0 + q4.y * w1 + q4.z * w2 + q4.w * w3;
            }
        }
        const float ba = battn[ja];
        #pragma unroll
        for (int k = 0; k < 2; ++k)
            aws[(qb + k) * 16 + ja] = s[k] + ba;
    }
    __syncthreads();   // coords + attn logits ready; q_tile reads complete

    // ---- softmax over 16 weights per query ----
    if (tid < QB) {
        float* a = &aws[tid * 16];
        float m = a[0];
        #pragma unroll
        for (int j = 1; j < 16; ++j) m = fmaxf(m, a[j]);
        float sum = 0.f;
        #pragma unroll
        for (int j = 0; j < 16; ++j) {
            const float e = __expf(a[j] - m);
            a[j] = e;
            sum += e;
        }
        const float r = 1.f / sum;
        #pragma unroll
        for (int j = 0; j < 16; ++j) a[j] *= r;
    }
    __syncthreads();

    // ---- build per-(q,point) sample table: folded weights + corner offsets ----
    #pragma unroll
    for (int e = tid; e < QB * 16; e += 256) {
        const int q = e >> 4;
        const int p = e & 15;
        const int l = p >> 3;
        const int H = l ? 64 : 128;
        const int W = l ? 128 : 256;
        const int S = l ? 32768 : 0;
        const float x   = coords[q * 32 + p * 2 + 0];
        const float y   = coords[q * 32 + p * 2 + 1];
        const float wgt = aws[q * 16 + p];
        const float xf = floorf(x), yf = floorf(y);
        const float lx = x - xf, ly = y - yf;
        const int x0 = (int)xf, y0 = (int)yf;
        const int x1 = x0 + 1, y1 = y0 + 1;
        const float hx = 1.f - lx, hy = 1.f - ly;
        float w00 = wgt * hx * hy;
        float w10 = wgt * lx * hy;
        float w01 = wgt * hx * ly;
        float w11 = wgt * lx * ly;
        if (x0 < 0 || x0 >= W) { w00 = 0.f; w01 = 0.f; }
        if (x1 < 0 || x1 >= W) { w10 = 0.f; w11 = 0.f; }
        if (y0 < 0 || y0 >= H) { w00 = 0.f; w10 = 0.f; }
        if (y1 < 0 || y1 >= H) { w01 = 0.f; w11 = 0.f; }
        const int cx0 = min(max(x0, 0), W - 1);
        const int cx1 = min(max(x1, 0), W - 1);
        const int cy0 = min(max(y0, 0), H - 1);
        const int cy1 = min(max(y1, 0), H - 1);
        wo_w[e] = make_float4(w00, w10, w01, w11);
        wo_o[e] = make_int4((S + cy0 * W + cx0) * 32,    // left , y0
                            (S + cy0 * W + cx1) * 32,    // right, y0
                            (S + cy1 * W + cx0) * 32,    // left , y1
                            (S + cy1 * W + cx1) * 32);   // right, y1
    }
    __syncthreads();

    // ---- gather: FULL wave per query ----
    // lanes 0-31: left-x corners; lanes 32-63: right-x corners. Each point
    // needs only 2 wave-loads (y0 row-pair, y1 row-pair), mostly 1KB
    // contiguous. 8-point batches -> 16 float4 loads in flight per wave.
    {
        const int wv   = tid >> 6;          // wave 0..3
        const int lane = tid & 63;
        const int half = lane >> 5;         // 0 = left(x0), 1 = right(x1)
        const int cl   = lane & 31;         // channel group
        const float4* vb = (const float4*)value
                         + (size_t)(blockIdx.x >> 10) * (40960 * 32);
        float4* og = (float4*)acc_out;

        #pragma unroll 1
        for (int i = 0; i < 8; ++i) {
            const int q = wv * 8 + i;
            const int base_e = q * 16;
            float ax = 0.f, ay = 0.f, az = 0.f, aw4 = 0.f;

            #pragma unroll 1
            for (int p0 = 0; p0 < 16; p0 += 8) {
                int   oa[8], ob[8];
                float wa[8], wb[8];
                #pragma unroll
                for (int pi = 0; pi < 8; ++pi) {
                    const float4 w = wo_w[base_e + p0 + pi];
                    const int4   o = wo_o[base_e + p0 + pi];
                    oa[pi] = (half ? o.y : o.x) + cl;
                    ob[pi] = (half ? o.w : o.z) + cl;
                    wa[pi] = half ? w.y : w.x;
                    wb[pi] = half ? w.w : w.z;
                }
                float4 vA[8], vB[8];
                #pragma unroll
                for (int pi = 0; pi < 8; ++pi) {
                    vA[pi] = vb[oa[pi]];
                    vB[pi] = vb[ob[pi]];
                }
                #pragma unroll
                for (int pi = 0; pi < 8; ++pi) {
                    ax  += wa[pi] * vA[pi].x + wb[pi] * vB[pi].x;
                    ay  += wa[pi] * vA[pi].y + wb[pi] * vB[pi].y;
                    az  += wa[pi] * vA[pi].z + wb[pi] * vB[pi].z;
                    aw4 += wa[pi] * vA[pi].w + wb[pi] * vB[pi].w;
                }
            }
            // combine left-half and right-half partial sums
            ax  += __shfl_xor(ax, 32, 64);
            ay  += __shfl_xor(ay, 32, 64);
            az  += __shfl_xor(az, 32, 64);
            aw4 += __shfl_xor(aw4, 32, 64);
            if (half == 0)
                og[(size_t)(r0 + q) * 32 + cl] = make_float4(ax, ay, az, aw4);
        }
    }
}

// In-place output GEMM: out[r,:] = acc[r,:] @ Wout + bout.
// 64 rows/block (LDS 49.4 KB -> 3 blocks/CU = 12 waves for latency hiding);
// W staged in LDS in two 64-ci halves. In-place safe: all reads of a block's
// rows precede its writes; blocks touch disjoint rows.
#define GR 64

__global__ __launch_bounds__(256, 3) void msda_out_gemm_kernel(
    const float* __restrict__ Wout,
    const float* __restrict__ bout,
    float* __restrict__ out)
{
    __shared__ __align__(16) float a_tile[GR * 68];    // 17.4 KB (pad 64->68)
    __shared__ __align__(16) float w_tile[64 * 128];   // 32 KB
    const int tid  = threadIdx.x;
    const int r0   = blockIdx.x * GR;
    const int trow = tid >> 4;    // 0..15 -> rows trow + 16*k, k<4
    const int tcol = tid & 15;    // cols tcol*8 .. tcol*8+7

    float4 o[4][2];
    #pragma unroll
    for (int k = 0; k < 4; ++k) {
        o[k][0] = make_float4(0.f, 0.f, 0.f, 0.f);
        o[k][1] = make_float4(0.f, 0.f, 0.f, 0.f);
    }

    #pragma unroll 1
    for (int h = 0; h < 2; ++h) {
        // stage a-tile: 64 rows x 16 float4 (ci = h*64 .. h*64+63)
        {
            const float4* src = (const float4*)out;
            #pragma unroll
            for (int i = 0; i < 4; ++i) {
                const int t  = tid + i * 256;      // 0..1023
                const int r  = t >> 4;
                const int c4 = t & 15;
                const float4 v = src[(size_t)(r0 + r) * 32 + h * 16 + c4];
                *(float4*)&a_tile[r * 68 + c4 * 4] = v;
            }
            // stage W rows h*64 .. h*64+63 (2048 float4, coalesced)
            const float4* ws = (const float4*)Wout + (size_t)h * 64 * 32;
            float4* wd = (float4*)w_tile;
            #pragma unroll
            for (int i = 0; i < 8; ++i)
                wd[tid + i * 256] = ws[tid + i * 256];
        }
        __syncthreads();

        #pragma unroll 1
        for (int c4 = 0; c4 < 16; ++c4) {
            float4 a4[4];
            #pragma unroll
            for (int k = 0; k < 4; ++k)
                a4[k] = *(const float4*)&a_tile[(trow + 16 * k) * 68 + c4 * 4];
            #pragma unroll
            for (int j = 0; j < 4; ++j) {
                const int ci = c4 * 4 + j;
                const float4 w0 = *(const float4*)&w_tile[ci * 128 + tcol * 8];
                const float4 w1 = *(const float4*)&w_tile[ci * 128 + tcol * 8 + 4];
                #pragma unroll
                for (int k = 0; k < 4; ++k) {
                    const float a = (j == 0) ? a4[k].x : (j == 1) ? a4[k].y
                                  : (j == 2) ? a4[k].z : a4[k].w;
                    o[k][0].x += a * w0.x; o[k][0].y += a * w0.y;
                    o[k][0].z += a * w0.z; o[k][0].w += a * w0.w;
                    o[k][1].x += a * w1.x; o[k][1].y += a * w1.y;
                    o[k][1].z += a * w1.z; o[k][1].w += a * w1.w;
                }
            }
        }
        __syncthreads();
    }

    const float4 b0 = ((const float4*)bout)[tcol * 2];
    const float4 b1 = ((const float4*)bout)[tcol * 2 + 1];
    float4* og = (float4*)out;
    #pragma unroll
    for (int k = 0; k < 4; ++k) {
        const size_t row = (size_t)(r0 + trow + 16 * k);
        float4 v0 = o[k][0], v1 = o[k][1];
        v0.x += b0.x; v0.y += b0.y; v0.z += b0.z; v0.w += b0.w;
        v1.x += b1.x; v1.y += b1.y; v1.z += b1.z; v1.w += b1.w;
        og[row * 32 + tcol * 2]     = v0;
        og[row * 32 + tcol * 2 + 1] = v1;
    }
}

extern "C" void kernel_launch(void* const* d_in, const int* in_sizes, int n_in,
                              void* d_out, int out_size, void* d_ws, size_t ws_size,
                              hipStream_t stream) {
    const float* query = (const float*)d_in[0];
    const float* value = (const float*)d_in[1];
    const float* qloc  = (const float*)d_in[2];
    // d_in[3] spatial_shapes, d_in[4] level_start_index: compile-time constants
    const float* Woff  = (const float*)d_in[5];
    const float* boff  = (const float*)d_in[6];
    const float* Wattn = (const float*)d_in[7];
    const float* battn = (const float*)d_in[8];
    const float* Wout  = (const float*)d_in[9];
    const float* bout  = (const float*)d_in[10];
    float* out = (float*)d_out;

    hipLaunchKernelGGL(msda_gather_kernel, dim3(65536 / QB), dim3(256), 0, stream,
                       query, value, qloc, Woff, boff, Wattn, battn, out);
    hipLaunchKernelGGL(msda_out_gemm_kernel, dim3(65536 / GR), dim3(256), 0, stream,
                       Wout, bout, out);
}

// Round 5
// 243.679 us; speedup vs baseline: 1.3676x; 1.1276x over previous
//
#include <hip/hip_runtime.h>
#include <hip/hip_fp16.h>

// Multi-Scale Deformable Attention:
//   [cvt value fp32->fp16 into d_ws] -> gather (fp16 value) -> in-place out GEMM
// BS=2, NQ=32768, C=128, NH=1, NL=2, NP=8, NV=40960
// level0 = 128x256 (start 0), level1 = 64x128 (start 32768)

#define QB 32  // queries per block (gather kernel)

struct __align__(8) h2x2 { __half2 a, b; };   // 4 fp16 channels (8 B)

// ---- value fp32 -> fp16 conversion (10.49M elements = 2.62M float4) ----
__global__ __launch_bounds__(256) void cvt_value_f16_kernel(
    const float4* __restrict__ in, h2x2* __restrict__ out, int n4)
{
    const int i = blockIdx.x * 256 + threadIdx.x;
    if (i < n4) {
        const float4 f = in[i];
        h2x2 h;
        h.a = __floats2half2_rn(f.x, f.y);
        h.b = __floats2half2_rn(f.z, f.w);
        out[i] = h;
    }
}

// ---------- shared prologue (phases 1-3 + softmax + sample table) ----------
// Used by both gather variants via a macro to keep them identical.
#define MSDA_PROLOGUE                                                          \
    float*  q_tile = (float*)smem_u;                                           \
    float4* wo_w   = (float4*)smem_u;                                          \
    int4*   wo_o   = (int4*)(smem_u + QB * 16 * 16);                           \
    const int tid = threadIdx.x;                                               \
    const int r0  = blockIdx.x * QB;                                           \
    {                                                                          \
        const float4* src = (const float4*)query + (size_t)r0 * 32;            \
        float4* dst = (float4*)q_tile;                                         \
        _Pragma("unroll")                                                      \
        for (int i = 0; i < 4; ++i)                                            \
            dst[tid + i * 256] = src[tid + i * 256];                           \
    }                                                                          \
    __syncthreads();                                                           \
    {                                                                          \
        const int jo = tid & 31;                                               \
        const int qb = (tid >> 5) * 4;                                         \
        float s[4] = {0.f, 0.f, 0.f, 0.f};                                     \
        for (int c4 = 0; c4 < 32; ++c4) {                                      \
            const float w0 = Woff[(c4 * 4 + 0) * 32 + jo];                     \
            const float w1 = Woff[(c4 * 4 + 1) * 32 + jo];                     \
            const float w2 = Woff[(c4 * 4 + 2) * 32 + jo];                     \
            const float w3 = Woff[(c4 * 4 + 3) * 32 + jo];                     \
            _Pragma("unroll")                                                  \
            for (int k = 0; k < 4; ++k) {                                      \
                const float4 q4 = *(const float4*)&q_tile[(qb + k) * 128 + c4 * 4]; \
                s[k] += q4.x * w0 + q4.y * w1 + q4.z * w2 + q4.w * w3;         \
            }                                                                  \
        }                                                                      \
        const int l = jo >> 4;                                                 \
        const int d = jo & 1;                                                  \
        const float scale = (d == 0) ? (l == 0 ? 256.f : 128.f)                \
                                     : (l == 0 ? 128.f : 64.f);                \
        const float bo = boff[jo];                                             \
        _Pragma("unroll")                                                      \
        for (int k = 0; k < 4; ++k) {                                          \
            const int row = r0 + qb + k;                                       \
            const float ql = qloc[row * 4 + l * 2 + d];                        \
            coords[(qb + k) * 32 + jo] = ql * scale + (s[k] + bo) - 0.5f;      \
        }                                                                      \
    }                                                                          \
    {                                                                          \
        const int ja = tid & 15;                                               \
        const int qb = (tid >> 4) * 2;                                         \
        float s[2] = {0.f, 0.f};                                               \
        for (int c4 = 0; c4 < 32; ++c4) {                                      \
            const float w0 = Wattn[(c4 * 4 + 0) * 16 + ja];                    \
            const float w1 = Wattn[(c4 * 4 + 1) * 16 + ja];                    \
            const float w2 = Wattn[(c4 * 4 + 2) * 16 + ja];                    \
            const float w3 = Wattn[(c4 * 4 + 3) * 16 + ja];                    \
            _Pragma("unroll")                                                  \
            for (int k = 0; k < 2; ++k) {                                      \
                const float4 q4 = *(const float4*)&q_tile[(qb + k) * 128 + c4 * 4]; \
                s[k] += q4.x * w0 + q4.y * w1 + q4.z * w2 + q4.w * w3;         \
            }                                                                  \
        }                                                                      \
        const float ba = battn[ja];                                            \
        _Pragma("unroll")                                                      \
        for (int k = 0; k < 2; ++k)                                            \
            aws[(qb + k) * 16 + ja] = s[k] + ba;                               \
    }                                                                          \
    __syncthreads();                                                           \
    if (tid < QB) {                                                            \
        float* a = &aws[tid * 16];                                             \
        float m = a[0];                                                        \
        _Pragma("unroll")                                                      \
        for (int j = 1; j < 16; ++j) m = fmaxf(m, a[j]);                       \
        float sum = 0.f;                                                       \
        _Pragma("unroll")                                                      \
        for (int j = 0; j < 16; ++j) {                                         \
            const float e = __expf(a[j] - m);                                  \
            a[j] = e;                                                          \
            sum += e;                                                          \
        }                                                                      \
        const float r = 1.f / sum;                                             \
        _Pragma("unroll")                                                      \
        for (int j = 0; j < 16; ++j) a[j] *= r;                                \
    }                                                                          \
    __syncthreads();                                                           \
    _Pragma("unroll")                                                          \
    for (int e = tid; e < QB * 16; e += 256) {                                 \
        const int q = e >> 4;                                                  \
        const int p = e & 15;                                                  \
        const int l = p >> 3;                                                  \
        const int H = l ? 64 : 128;                                            \
        const int W = l ? 128 : 256;                                           \
        const int S = l ? 32768 : 0;                                           \
        const float x   = coords[q * 32 + p * 2 + 0];                          \
        const float y   = coords[q * 32 + p * 2 + 1];                          \
        const float wgt = aws[q * 16 + p];                                     \
        const float xf = floorf(x), yf = floorf(y);                            \
        const float lx = x - xf, ly = y - yf;                                  \
        const int x0 = (int)xf, y0 = (int)yf;                                  \
        const int x1 = x0 + 1, y1 = y0 + 1;                                    \
        const float hx = 1.f - lx, hy = 1.f - ly;                              \
        float w00 = wgt * hx * hy;                                             \
        float w10 = wgt * lx * hy;                                             \
        float w01 = wgt * hx * ly;                                             \
        float w11 = wgt * lx * ly;                                             \
        if (x0 < 0 || x0 >= W) { w00 = 0.f; w01 = 0.f; }                       \
        if (x1 < 0 || x1 >= W) { w10 = 0.f; w11 = 0.f; }                       \
        if (y0 < 0 || y0 >= H) { w00 = 0.f; w10 = 0.f; }                       \
        if (y1 < 0 || y1 >= H) { w01 = 0.f; w11 = 0.f; }                       \
        const int cx0 = min(max(x0, 0), W - 1);                                \
        const int cx1 = min(max(x1, 0), W - 1);                                \
        const int cy0 = min(max(y0, 0), H - 1);                                \
        const int cy1 = min(max(y1, 0), H - 1);                                \
        wo_w[e] = make_float4(w00, w10, w01, w11);                             \
        wo_o[e] = make_int4((S + cy0 * W + cx0) * 32,                          \
                            (S + cy0 * W + cx1) * 32,                          \
                            (S + cy1 * W + cx0) * 32,                          \
                            (S + cy1 * W + cx1) * 32);                        \
    }                                                                          \
    __syncthreads();

// ---- gather, fp16 value path ----
__global__ __launch_bounds__(256, 4) void msda_gather_f16_kernel(
    const float* __restrict__ query,
    const h2x2*  __restrict__ value_h,   // fp16 value in d_ws
    const float* __restrict__ qloc,
    const float* __restrict__ Woff,
    const float* __restrict__ boff,
    const float* __restrict__ Wattn,
    const float* __restrict__ battn,
    float* __restrict__ acc_out)
{
    __shared__ __align__(16) char smem_u[QB * 128 * 4];
    __shared__ float coords[QB * 32];
    __shared__ float aws[QB * 16];
    MSDA_PROLOGUE

    // full wave per query: lanes 0-31 left-x corner, 32-63 right-x corner.
    // fp16 rows are 256 B; offsets in wo_o are row*32 = 8B-element units.
    {
        const int wv   = tid >> 6;
        const int lane = tid & 63;
        const int half = lane >> 5;
        const int cl   = lane & 31;
        const h2x2* vb = value_h + (size_t)(blockIdx.x >> 10) * (40960 * 32);
        float4* og = (float4*)acc_out;

        #pragma unroll 1
        for (int i = 0; i < 8; ++i) {
            const int q = wv * 8 + i;
            const int base_e = q * 16;
            float ax = 0.f, ay = 0.f, az = 0.f, aw4 = 0.f;

            // all 16 points batched: 32 x 8B loads in flight
            int   oa[16], ob[16];
            float wa[16], wb[16];
            #pragma unroll
            for (int p = 0; p < 16; ++p) {
                const float4 w = wo_w[base_e + p];
                const int4   o = wo_o[base_e + p];
                oa[p] = (half ? o.y : o.x) + cl;
                ob[p] = (half ? o.w : o.z) + cl;
                wa[p] = half ? w.y : w.x;
                wb[p] = half ? w.w : w.z;
            }
            h2x2 vA[16], vB[16];
            #pragma unroll
            for (int p = 0; p < 16; ++p) {
                vA[p] = vb[oa[p]];
                vB[p] = vb[ob[p]];
            }
            #pragma unroll
            for (int p = 0; p < 16; ++p) {
                const float2 a0 = __half22float2(vA[p].a);
                const float2 a1 = __half22float2(vA[p].b);
                const float2 b0 = __half22float2(vB[p].a);
                const float2 b1 = __half22float2(vB[p].b);
                ax  += wa[p] * a0.x + wb[p] * b0.x;
                ay  += wa[p] * a0.y + wb[p] * b0.y;
                az  += wa[p] * a1.x + wb[p] * b1.x;
                aw4 += wa[p] * a1.y + wb[p] * b1.y;
            }
            ax  += __shfl_xor(ax, 32, 64);
            ay  += __shfl_xor(ay, 32, 64);
            az  += __shfl_xor(az, 32, 64);
            aw4 += __shfl_xor(aw4, 32, 64);
            if (half == 0)
                og[(size_t)(r0 + q) * 32 + cl] = make_float4(ax, ay, az, aw4);
        }
    }
}

// ---- gather, fp32 fallback (ws too small) — R4 version ----
__global__ __launch_bounds__(256, 4) void msda_gather_f32_kernel(
    const float* __restrict__ query,
    const float* __restrict__ value,
    const float* __restrict__ qloc,
    const float* __restrict__ Woff,
    const float* __restrict__ boff,
    const float* __restrict__ Wattn,
    const float* __restrict__ battn,
    float* __restrict__ acc_out)
{
    __shared__ __align__(16) char smem_u[QB * 128 * 4];
    __shared__ float coords[QB * 32];
    __shared__ float aws[QB * 16];
    MSDA_PROLOGUE

    {
        const int wv   = tid >> 6;
        const int lane = tid & 63;
        const int half = lane >> 5;
        const int cl   = lane & 31;
        const float4* vb = (const float4*)value
                         + (size_t)(blockIdx.x >> 10) * (40960 * 32);
        float4* og = (float4*)acc_out;

        #pragma unroll 1
        for (int i = 0; i < 8; ++i) {
            const int q = wv * 8 + i;
            const int base_e = q * 16;
            float ax = 0.f, ay = 0.f, az = 0.f, aw4 = 0.f;

            #pragma unroll 1
            for (int p0 = 0; p0 < 16; p0 += 8) {
                int   oa[8], ob[8];
                float wa[8], wb[8];
                #pragma unroll
                for (int pi = 0; pi < 8; ++pi) {
                    const float4 w = wo_w[base_e + p0 + pi];
                    const int4   o = wo_o[base_e + p0 + pi];
                    oa[pi] = (half ? o.y : o.x) + cl;
                    ob[pi] = (half ? o.w : o.z) + cl;
                    wa[pi] = half ? w.y : w.x;
                    wb[pi] = half ? w.w : w.z;
                }
                float4 vA[8], vB[8];
                #pragma unroll
                for (int pi = 0; pi < 8; ++pi) {
                    vA[pi] = vb[oa[pi]];
                    vB[pi] = vb[ob[pi]];
                }
                #pragma unroll
                for (int pi = 0; pi < 8; ++pi) {
                    ax  += wa[pi] * vA[pi].x + wb[pi] * vB[pi].x;
                    ay  += wa[pi] * vA[pi].y + wb[pi] * vB[pi].y;
                    az  += wa[pi] * vA[pi].z + wb[pi] * vB[pi].z;
                    aw4 += wa[pi] * vA[pi].w + wb[pi] * vB[pi].w;
                }
            }
            ax  += __shfl_xor(ax, 32, 64);
            ay  += __shfl_xor(ay, 32, 64);
            az  += __shfl_xor(az, 32, 64);
            aw4 += __shfl_xor(aw4, 32, 64);
            if (half == 0)
                og[(size_t)(r0 + q) * 32 + cl] = make_float4(ax, ay, az, aw4);
        }
    }
}

// In-place output GEMM: out[r,:] = acc[r,:] @ Wout + bout. 64 rows/block.
#define GR 64

__global__ __launch_bounds__(256, 3) void msda_out_gemm_kernel(
    const float* __restrict__ Wout,
    const float* __restrict__ bout,
    float* __restrict__ out)
{
    __shared__ __align__(16) float a_tile[GR * 68];
    __shared__ __align__(16) float w_tile[64 * 128];
    const int tid  = threadIdx.x;
    const int r0   = blockIdx.x * GR;
    const int trow = tid >> 4;
    const int tcol = tid & 15;

    float4 o[4][2];
    #pragma unroll
    for (int k = 0; k < 4; ++k) {
        o[k][0] = make_float4(0.f, 0.f, 0.f, 0.f);
        o[k][1] = make_float4(0.f, 0.f, 0.f, 0.f);
    }

    #pragma unroll 1
    for (int h = 0; h < 2; ++h) {
        {
            const float4* src = (const float4*)out;
            #pragma unroll
            for (int i = 0; i < 4; ++i) {
                const int t  = tid + i * 256;
                const int r  = t >> 4;
                const int c4 = t & 15;
                const float4 v = src[(size_t)(r0 + r) * 32 + h * 16 + c4];
                *(float4*)&a_tile[r * 68 + c4 * 4] = v;
            }
            const float4* ws = (const float4*)Wout + (size_t)h * 64 * 32;
            float4* wd = (float4*)w_tile;
            #pragma unroll
            for (int i = 0; i < 8; ++i)
                wd[tid + i * 256] = ws[tid + i * 256];
        }
        __syncthreads();

        #pragma unroll 1
        for (int c4 = 0; c4 < 16; ++c4) {
            float4 a4[4];
            #pragma unroll
            for (int k = 0; k < 4; ++k)
                a4[k] = *(const float4*)&a_tile[(trow + 16 * k) * 68 + c4 * 4];
            #pragma unroll
            for (int j = 0; j < 4; ++j) {
                const int ci = c4 * 4 + j;
                const float4 w0 = *(const float4*)&w_tile[ci * 128 + tcol * 8];
                const float4 w1 = *(const float4*)&w_tile[ci * 128 + tcol * 8 + 4];
                #pragma unroll
                for (int k = 0; k < 4; ++k) {
                    const float a = (j == 0) ? a4[k].x : (j == 1) ? a4[k].y
                                  : (j == 2) ? a4[k].z : a4[k].w;
                    o[k][0].x += a * w0.x; o[k][0].y += a * w0.y;
                    o[k][0].z += a * w0.z; o[k][0].w += a * w0.w;
                    o[k][1].x += a * w1.x; o[k][1].y += a * w1.y;
                    o[k][1].z += a * w1.z; o[k][1].w += a * w1.w;
                }
            }
        }
        __syncthreads();
    }

    const float4 b0 = ((const float4*)bout)[tcol * 2];
    const float4 b1 = ((const float4*)bout)[tcol * 2 + 1];
    float4* og = (float4*)out;
    #pragma unroll
    for (int k = 0; k < 4; ++k) {
        const size_t row = (size_t)(r0 + trow + 16 * k);
        float4 v0 = o[k][0], v1 = o[k][1];
        v0.x += b0.x; v0.y += b0.y; v0.z += b0.z; v0.w += b0.w;
        v1.x += b1.x; v1.y += b1.y; v1.z += b1.z; v1.w += b1.w;
        og[row * 32 + tcol * 2]     = v0;
        og[row * 32 + tcol * 2 + 1] = v1;
    }
}

extern "C" void kernel_launch(void* const* d_in, const int* in_sizes, int n_in,
                              void* d_out, int out_size, void* d_ws, size_t ws_size,
                              hipStream_t stream) {
    const float* query = (const float*)d_in[0];
    const float* value = (const float*)d_in[1];
    const float* qloc  = (const float*)d_in[2];
    const float* Woff  = (const float*)d_in[5];
    const float* boff  = (const float*)d_in[6];
    const float* Wattn = (const float*)d_in[7];
    const float* battn = (const float*)d_in[8];
    const float* Wout  = (const float*)d_in[9];
    const float* bout  = (const float*)d_in[10];
    float* out = (float*)d_out;

    const int n_val = 2 * 40960 * 128;               // 10,485,760 floats
    const size_t f16_bytes = (size_t)n_val * 2;       // 20,971,520 B

    if (ws_size >= f16_bytes) {
        h2x2* val16 = (h2x2*)d_ws;
        const int n4 = n_val / 4;                     // 2,621,440 float4s
        hipLaunchKernelGGL(cvt_value_f16_kernel, dim3((n4 + 255) / 256), dim3(256),
                           0, stream, (const float4*)value, val16, n4);
        hipLaunchKernelGGL(msda_gather_f16_kernel, dim3(65536 / QB), dim3(256),
                           0, stream,
                           query, (const h2x2*)val16, qloc, Woff, boff, Wattn, battn, out);
    } else {
        hipLaunchKernelGGL(msda_gather_f32_kernel, dim3(65536 / QB), dim3(256),
                           0, stream,
                           query, value, qloc, Woff, boff, Wattn, battn, out);
    }
    hipLaunchKernelGGL(msda_out_gemm_kernel, dim3(65536 / GR), dim3(256), 0, stream,
                       Wout, bout, out);
}

// Round 6
// 238.442 us; speedup vs baseline: 1.3977x; 1.0220x over previous
//
#include <hip/hip_runtime.h>
#include <hip/hip_fp16.h>

// Multi-Scale Deformable Attention:
//   cvt value fp32->fp16 (d_ws) -> gather (fp16, fma_mix) -> in-place out GEMM
// BS=2, NQ=32768, C=128, NH=1, NL=2, NP=8, NV=40960
// level0 = 128x256 (start 0), level1 = 64x128 (start 32768)

#define QB 32  // queries per block (gather kernel)

struct __align__(8) h2x2 { __half2 a, b; };   // 4 fp16 channels (8 B)

// ---- value fp32 -> fp16 conversion ----
__global__ __launch_bounds__(256) void cvt_value_f16_kernel(
    const float4* __restrict__ in, h2x2* __restrict__ out, int n4)
{
    const int i = blockIdx.x * 256 + threadIdx.x;
    if (i < n4) {
        const float4 f = in[i];
        h2x2 h;
        h.a = __floats2half2_rn(f.x, f.y);
        h.b = __floats2half2_rn(f.z, f.w);
        out[i] = h;
    }
}

// ---------- shared prologue (phases 1-3 + softmax + per-half sample table) ---
// Table: tab[(q*16+p)*2 + half] = int4{ bits(wa), bits(wb), oa, ob }
//   half=0 (x0 corner): wa=w00, wb=w01, oa=idx(y0,x0)*32, ob=idx(y1,x0)*32
//   half=1 (x1 corner): wa=w10, wb=w11, oa=idx(y0,x1)*32, ob=idx(y1,x1)*32
// Offsets are in 8B-units for fp16 (h2x2) and 16B-units for fp32 (float4) —
// identical numeric value (pixel*32) for both.
#define MSDA_PROLOGUE                                                          \
    float* q_tile = (float*)smem_u;                                            \
    int4*  tab    = (int4*)smem_u;                                             \
    const int tid = threadIdx.x;                                               \
    const int r0  = blockIdx.x * QB;                                           \
    {                                                                          \
        const float4* src = (const float4*)query + (size_t)r0 * 32;            \
        float4* dst = (float4*)q_tile;                                         \
        _Pragma("unroll")                                                      \
        for (int i = 0; i < 4; ++i)                                            \
            dst[tid + i * 256] = src[tid + i * 256];                           \
    }                                                                          \
    __syncthreads();                                                           \
    {                                                                          \
        const int jo = tid & 31;                                               \
        const int qb = (tid >> 5) * 4;                                         \
        float s[4] = {0.f, 0.f, 0.f, 0.f};                                     \
        for (int c4 = 0; c4 < 32; ++c4) {                                      \
            const float w0 = Woff[(c4 * 4 + 0) * 32 + jo];                     \
            const float w1 = Woff[(c4 * 4 + 1) * 32 + jo];                     \
            const float w2 = Woff[(c4 * 4 + 2) * 32 + jo];                     \
            const float w3 = Woff[(c4 * 4 + 3) * 32 + jo];                     \
            _Pragma("unroll")                                                  \
            for (int k = 0; k < 4; ++k) {                                      \
                const float4 q4 = *(const float4*)&q_tile[(qb + k) * 128 + c4 * 4]; \
                s[k] += q4.x * w0 + q4.y * w1 + q4.z * w2 + q4.w * w3;         \
            }                                                                  \
        }                                                                      \
        const int l = jo >> 4;                                                 \
        const int d = jo & 1;                                                  \
        const float scale = (d == 0) ? (l == 0 ? 256.f : 128.f)                \
                                     : (l == 0 ? 128.f : 64.f);                \
        const float bo = boff[jo];                                             \
        _Pragma("unroll")                                                      \
        for (int k = 0; k < 4; ++k) {                                          \
            const int row = r0 + qb + k;                                       \
            const float ql = qloc[row * 4 + l * 2 + d];                        \
            coords[(qb + k) * 32 + jo] = ql * scale + (s[k] + bo) - 0.5f;      \
        }                                                                      \
    }                                                                          \
    {                                                                          \
        const int ja = tid & 15;                                               \
        const int qb = (tid >> 4) * 2;                                         \
        float s[2] = {0.f, 0.f};                                               \
        for (int c4 = 0; c4 < 32; ++c4) {                                      \
            const float w0 = Wattn[(c4 * 4 + 0) * 16 + ja];                    \
            const float w1 = Wattn[(c4 * 4 + 1) * 16 + ja];                    \
            const float w2 = Wattn[(c4 * 4 + 2) * 16 + ja];                    \
            const float w3 = Wattn[(c4 * 4 + 3) * 16 + ja];                    \
            _Pragma("unroll")                                                  \
            for (int k = 0; k < 2; ++k) {                                      \
                const float4 q4 = *(const float4*)&q_tile[(qb + k) * 128 + c4 * 4]; \
                s[k] += q4.x * w0 + q4.y * w1 + q4.z * w2 + q4.w * w3;         \
            }                                                                  \
        }                                                                      \
        const float ba = battn[ja];                                            \
        _Pragma("unroll")                                                      \
        for (int k = 0; k < 2; ++k)                                            \
            aws[(qb + k) * 16 + ja] = s[k] + ba;                               \
    }                                                                          \
    __syncthreads();                                                           \
    if (tid < QB) {                                                            \
        float* a = &aws[tid * 16];                                             \
        float m = a[0];                                                        \
        _Pragma("unroll")                                                      \
        for (int j = 1; j < 16; ++j) m = fmaxf(m, a[j]);                       \
        float sum = 0.f;                                                       \
        _Pragma("unroll")                                                      \
        for (int j = 0; j < 16; ++j) {                                         \
            const float e = __expf(a[j] - m);                                  \
            a[j] = e;                                                          \
            sum += e;                                                          \
        }                                                                      \
        const float r = 1.f / sum;                                             \
        _Pragma("unroll")                                                      \
        for (int j = 0; j < 16; ++j) a[j] *= r;                                \
    }                                                                          \
    __syncthreads();                                                           \
    _Pragma("unroll")                                                          \
    for (int e = tid; e < QB * 16; e += 256) {                                 \
        const int q = e >> 4;                                                  \
        const int p = e & 15;                                                  \
        const int l = p >> 3;                                                  \
        const int H = l ? 64 : 128;                                            \
        const int W = l ? 128 : 256;                                           \
        const int S = l ? 32768 : 0;                                           \
        const float x   = coords[q * 32 + p * 2 + 0];                          \
        const float y   = coords[q * 32 + p * 2 + 1];                          \
        const float wgt = aws[q * 16 + p];                                     \
        const float xf = floorf(x), yf = floorf(y);                            \
        const float lx = x - xf, ly = y - yf;                                  \
        const int x0 = (int)xf, y0 = (int)yf;                                  \
        const int x1 = x0 + 1, y1 = y0 + 1;                                    \
        const float hx = 1.f - lx, hy = 1.f - ly;                              \
        float w00 = wgt * hx * hy;                                             \
        float w10 = wgt * lx * hy;                                             \
        float w01 = wgt * hx * ly;                                             \
        float w11 = wgt * lx * ly;                                             \
        if (x0 < 0 || x0 >= W) { w00 = 0.f; w01 = 0.f; }                       \
        if (x1 < 0 || x1 >= W) { w10 = 0.f; w11 = 0.f; }                       \
        if (y0 < 0 || y0 >= H) { w00 = 0.f; w10 = 0.f; }                       \
        if (y1 < 0 || y1 >= H) { w01 = 0.f; w11 = 0.f; }                       \
        const int cx0 = min(max(x0, 0), W - 1);                                \
        const int cx1 = min(max(x1, 0), W - 1);                                \
        const int cy0 = min(max(y0, 0), H - 1);                                \
        const int cy1 = min(max(y1, 0), H - 1);                                \
        int4 e0, e1;                                                           \
        e0.x = __float_as_int(w00); e0.y = __float_as_int(w01);                \
        e0.z = (S + cy0 * W + cx0) * 32; e0.w = (S + cy1 * W + cx0) * 32;      \
        e1.x = __float_as_int(w10); e1.y = __float_as_int(w11);                \
        e1.z = (S + cy0 * W + cx1) * 32; e1.w = (S + cy1 * W + cx1) * 32;      \
        tab[e * 2]     = e0;                                                   \
        tab[e * 2 + 1] = e1;                                                   \
    }                                                                          \
    __syncthreads();

// ---- gather, fp16 value path ----
__global__ __launch_bounds__(256, 4) void msda_gather_f16_kernel(
    const float* __restrict__ query,
    const h2x2*  __restrict__ value_h,
    const float* __restrict__ qloc,
    const float* __restrict__ Woff,
    const float* __restrict__ boff,
    const float* __restrict__ Wattn,
    const float* __restrict__ battn,
    float* __restrict__ acc_out)
{
    __shared__ __align__(16) char smem_u[QB * 128 * 4];
    __shared__ float coords[QB * 32];
    __shared__ float aws[QB * 16];
    MSDA_PROLOGUE

    {
        const int wv   = tid >> 6;
        const int lane = tid & 63;
        const int half = lane >> 5;
        const int cl   = lane & 31;
        const h2x2* vb = value_h + (size_t)(blockIdx.x >> 10) * (40960 * 32);
        float4* og = (float4*)acc_out;

        #pragma unroll 1
        for (int i = 0; i < 8; ++i) {
            const int q = wv * 8 + i;
            float ax = 0.f, ay = 0.f, az = 0.f, aw4 = 0.f;

            #pragma unroll 1
            for (int p0 = 0; p0 < 16; p0 += 8) {
                float wa[8], wb[8];
                int   oa[8], ob[8];
                #pragma unroll
                for (int pi = 0; pi < 8; ++pi) {
                    const int4 t = tab[((q * 16 + p0 + pi) << 1) + half];
                    wa[pi] = __int_as_float(t.x);
                    wb[pi] = __int_as_float(t.y);
                    oa[pi] = t.z + cl;
                    ob[pi] = t.w + cl;
                }
                h2x2 vA[8], vB[8];
                #pragma unroll
                for (int pi = 0; pi < 8; ++pi) {
                    vA[pi] = vb[oa[pi]];
                    vB[pi] = vb[ob[pi]];
                }
                #pragma unroll
                for (int pi = 0; pi < 8; ++pi) {
                    // fp16 operand folded into fp32 FMA (v_fma_mix)
                    ax  += wa[pi] * __low2float(vA[pi].a);
                    ay  += wa[pi] * __high2float(vA[pi].a);
                    az  += wa[pi] * __low2float(vA[pi].b);
                    aw4 += wa[pi] * __high2float(vA[pi].b);
                    ax  += wb[pi] * __low2float(vB[pi].a);
                    ay  += wb[pi] * __high2float(vB[pi].a);
                    az  += wb[pi] * __low2float(vB[pi].b);
                    aw4 += wb[pi] * __high2float(vB[pi].b);
                }
            }
            ax  += __shfl_xor(ax, 32, 64);
            ay  += __shfl_xor(ay, 32, 64);
            az  += __shfl_xor(az, 32, 64);
            aw4 += __shfl_xor(aw4, 32, 64);
            if (half == 0)
                og[(size_t)(r0 + q) * 32 + cl] = make_float4(ax, ay, az, aw4);
        }
    }
}

// ---- gather, fp32 fallback (ws too small) ----
__global__ __launch_bounds__(256, 4) void msda_gather_f32_kernel(
    const float* __restrict__ query,
    const float* __restrict__ value,
    const float* __restrict__ qloc,
    const float* __restrict__ Woff,
    const float* __restrict__ boff,
    const float* __restrict__ Wattn,
    const float* __restrict__ battn,
    float* __restrict__ acc_out)
{
    __shared__ __align__(16) char smem_u[QB * 128 * 4];
    __shared__ float coords[QB * 32];
    __shared__ float aws[QB * 16];
    MSDA_PROLOGUE

    {
        const int wv   = tid >> 6;
        const int lane = tid & 63;
        const int half = lane >> 5;
        const int cl   = lane & 31;
        const float4* vb = (const float4*)value
                         + (size_t)(blockIdx.x >> 10) * (40960 * 32);
        float4* og = (float4*)acc_out;

        #pragma unroll 1
        for (int i = 0; i < 8; ++i) {
            const int q = wv * 8 + i;
            float ax = 0.f, ay = 0.f, az = 0.f, aw4 = 0.f;

            #pragma unroll 1
            for (int p0 = 0; p0 < 16; p0 += 8) {
                float wa[8], wb[8];
                int   oa[8], ob[8];
                #pragma unroll
                for (int pi = 0; pi < 8; ++pi) {
                    const int4 t = tab[((q * 16 + p0 + pi) << 1) + half];
                    wa[pi] = __int_as_float(t.x);
                    wb[pi] = __int_as_float(t.y);
                    oa[pi] = t.z + cl;
                    ob[pi] = t.w + cl;
                }
                float4 vA[8], vB[8];
                #pragma unroll
                for (int pi = 0; pi < 8; ++pi) {
                    vA[pi] = vb[oa[pi]];
                    vB[pi] = vb[ob[pi]];
                }
                #pragma unroll
                for (int pi = 0; pi < 8; ++pi) {
                    ax  += wa[pi] * vA[pi].x + wb[pi] * vB[pi].x;
                    ay  += wa[pi] * vA[pi].y + wb[pi] * vB[pi].y;
                    az  += wa[pi] * vA[pi].z + wb[pi] * vB[pi].z;
                    aw4 += wa[pi] * vA[pi].w + wb[pi] * vB[pi].w;
                }
            }
            ax  += __shfl_xor(ax, 32, 64);
            ay  += __shfl_xor(ay, 32, 64);
            az  += __shfl_xor(az, 32, 64);
            aw4 += __shfl_xor(aw4, 32, 64);
            if (half == 0)
                og[(size_t)(r0 + q) * 32 + cl] = make_float4(ax, ay, az, aw4);
        }
    }
}

// In-place output GEMM: out[r,:] = acc[r,:] @ Wout + bout.
// 128 rows/block, 8 rows x 8 cols per thread (cols tcol*4 and 64+tcol*4 —
// 2-way LDS bank aliasing = free). LDS 66.8 KB -> 2 blocks/CU; FMA- and
// LDS-balanced (~14 us each). In-place safe: all reads precede all writes
// within a block; blocks touch disjoint rows.
#define GR 128

__global__ __launch_bounds__(256, 2) void msda_out_gemm_kernel(
    const float* __restrict__ Wout,
    const float* __restrict__ bout,
    float* __restrict__ out)
{
    __shared__ __align__(16) float a_tile[GR * 68];    // 34.8 KB (64 ci-half, pad 68)
    __shared__ __align__(16) float w_tile[64 * 128];   // 32 KB
    const int tid  = threadIdx.x;
    const int r0   = blockIdx.x * GR;
    const int trow = tid >> 4;    // 0..15 -> rows trow + 16*k, k<8
    const int tcol = tid & 15;    // cols tcol*4..+3 and 64+tcol*4..+3

    float4 o[8][2];
    #pragma unroll
    for (int k = 0; k < 8; ++k) {
        o[k][0] = make_float4(0.f, 0.f, 0.f, 0.f);
        o[k][1] = make_float4(0.f, 0.f, 0.f, 0.f);
    }

    #pragma unroll 1
    for (int h = 0; h < 2; ++h) {
        // stage a-tile: 128 rows x 16 float4 (ci = h*64 .. h*64+63)
        {
            const float4* src = (const float4*)out;
            #pragma unroll
            for (int i = 0; i < 8; ++i) {
                const int t  = tid + i * 256;      // 0..2047
                const int r  = t >> 4;
                const int c4 = t & 15;
                const float4 v = src[(size_t)(r0 + r) * 32 + h * 16 + c4];
                *(float4*)&a_tile[r * 68 + c4 * 4] = v;
            }
            // stage W rows h*64 .. h*64+63 (2048 float4, coalesced)
            const float4* ws = (const float4*)Wout + (size_t)h * 64 * 32;
            float4* wd = (float4*)w_tile;
            #pragma unroll
            for (int i = 0; i < 8; ++i)
                wd[tid + i * 256] = ws[tid + i * 256];
        }
        __syncthreads();

        #pragma unroll 1
        for (int c4 = 0; c4 < 16; ++c4) {
            float4 a4[8];
            #pragma unroll
            for (int k = 0; k < 8; ++k)
                a4[k] = *(const float4*)&a_tile[(trow + 16 * k) * 68 + c4 * 4];
            #pragma unroll
            for (int j = 0; j < 4; ++j) {
                const int ci = c4 * 4 + j;
                const float4 w0 = *(const float4*)&w_tile[ci * 128 + tcol * 4];
                const float4 w1 = *(const float4*)&w_tile[ci * 128 + 64 + tcol * 4];
                #pragma unroll
                for (int k = 0; k < 8; ++k) {
                    const float a = (j == 0) ? a4[k].x : (j == 1) ? a4[k].y
                                  : (j == 2) ? a4[k].z : a4[k].w;
                    o[k][0].x += a * w0.x; o[k][0].y += a * w0.y;
                    o[k][0].z += a * w0.z; o[k][0].w += a * w0.w;
                    o[k][1].x += a * w1.x; o[k][1].y += a * w1.y;
                    o[k][1].z += a * w1.z; o[k][1].w += a * w1.w;
                }
            }
        }
        __syncthreads();
    }

    const float4 b0 = ((const float4*)bout)[tcol];        // cols tcol*4..+3
    const float4 b1 = ((const float4*)bout)[16 + tcol];   // cols 64+tcol*4..+3
    float4* og = (float4*)out;
    #pragma unroll
    for (int k = 0; k < 8; ++k) {
        const size_t row = (size_t)(r0 + trow + 16 * k);
        float4 v0 = o[k][0], v1 = o[k][1];
        v0.x += b0.x; v0.y += b0.y; v0.z += b0.z; v0.w += b0.w;
        v1.x += b1.x; v1.y += b1.y; v1.z += b1.z; v1.w += b1.w;
        og[row * 32 + tcol]      = v0;
        og[row * 32 + 16 + tcol] = v1;
    }
}

extern "C" void kernel_launch(void* const* d_in, const int* in_sizes, int n_in,
                              void* d_out, int out_size, void* d_ws, size_t ws_size,
                              hipStream_t stream) {
    const float* query = (const float*)d_in[0];
    const float* value = (const float*)d_in[1];
    const float* qloc  = (const float*)d_in[2];
    const float* Woff  = (const float*)d_in[5];
    const float* boff  = (const float*)d_in[6];
    const float* Wattn = (const float*)d_in[7];
    const float* battn = (const float*)d_in[8];
    const float* Wout  = (const float*)d_in[9];
    const float* bout  = (const float*)d_in[10];
    float* out = (float*)d_out;

    const int n_val = 2 * 40960 * 128;
    const size_t f16_bytes = (size_t)n_val * 2;

    if (ws_size >= f16_bytes) {
        h2x2* val16 = (h2x2*)d_ws;
        const int n4 = n_val / 4;
        hipLaunchKernelGGL(cvt_value_f16_kernel, dim3((n4 + 255) / 256), dim3(256),
                           0, stream, (const float4*)value, val16, n4);
        hipLaunchKernelGGL(msda_gather_f16_kernel, dim3(65536 / QB), dim3(256),
                           0, stream,
                           query, (const h2x2*)val16, qloc, Woff, boff, Wattn, battn, out);
    } else {
        hipLaunchKernelGGL(msda_gather_f32_kernel, dim3(65536 / QB), dim3(256),
                           0, stream,
                           query, value, qloc, Woff, boff, Wattn, battn, out);
    }
    hipLaunchKernelGGL(msda_out_gemm_kernel, dim3(65536 / GR), dim3(256), 0, stream,
                       Wout, bout, out);
}

// Round 7
// 227.719 us; speedup vs baseline: 1.4635x; 1.0471x over previous
//
#include <hip/hip_runtime.h>
#include <hip/hip_fp16.h>

// Multi-Scale Deformable Attention:
//   cvt value fp32->fp16 (d_ws) + Wout^T fp16 (ws tail) -> gather (fp16)
//   -> MFMA fp16 output GEMM (in-place on d_out)
// BS=2, NQ=32768, C=128, NH=1, NL=2, NP=8, NV=40960
// level0 = 128x256 (start 0), level1 = 64x128 (start 32768)

#define QB 32  // queries per block (gather kernel)

struct __align__(8) h2x2 { __half2 a, b; };   // 4 fp16 channels (8 B)

typedef _Float16 f16x8 __attribute__((ext_vector_type(8)));
typedef _Float16 f16x4 __attribute__((ext_vector_type(4)));
typedef float    f32x4 __attribute__((ext_vector_type(4)));

// ---- value fp32 -> fp16 conversion ----
__global__ __launch_bounds__(256) void cvt_value_f16_kernel(
    const float4* __restrict__ in, h2x2* __restrict__ out, int n4)
{
    const int i = blockIdx.x * 256 + threadIdx.x;
    if (i < n4) {
        const float4 f = in[i];
        h2x2 h;
        h.a = __floats2half2_rn(f.x, f.y);
        h.b = __floats2half2_rn(f.z, f.w);
        out[i] = h;
    }
}

// ---- Wout (fp32 [k][n]) -> wTg (fp16 [n][k]) one-block transpose ----
__global__ __launch_bounds__(256) void wout_transpose_kernel(
    const float* __restrict__ Wout, _Float16* __restrict__ wTg)
{
    __shared__ float t[128 * 129];
    const int tid = threadIdx.x;
    #pragma unroll
    for (int i = 0; i < 16; ++i) {
        const int f  = tid + i * 256;     // 0..4095 float4s
        const int k  = f >> 5;
        const int c4 = f & 31;
        const float4 v = ((const float4*)Wout)[k * 32 + c4];
        t[k * 129 + c4 * 4 + 0] = v.x;
        t[k * 129 + c4 * 4 + 1] = v.y;
        t[k * 129 + c4 * 4 + 2] = v.z;
        t[k * 129 + c4 * 4 + 3] = v.w;
    }
    __syncthreads();
    #pragma unroll
    for (int i = 0; i < 64; ++i) {
        const int f = tid + i * 256;      // 0..16383
        const int n = f >> 7;
        const int k = f & 127;
        wTg[n * 128 + k] = (_Float16)t[k * 129 + n];
    }
}

// ---------- shared prologue (phases 1-3 + softmax + per-half sample table) ---
#define MSDA_PROLOGUE                                                          \
    float* q_tile = (float*)smem_u;                                            \
    int4*  tab    = (int4*)smem_u;                                             \
    const int tid = threadIdx.x;                                               \
    const int r0  = blockIdx.x * QB;                                           \
    {                                                                          \
        const float4* src = (const float4*)query + (size_t)r0 * 32;            \
        float4* dst = (float4*)q_tile;                                         \
        _Pragma("unroll")                                                      \
        for (int i = 0; i < 4; ++i)                                            \
            dst[tid + i * 256] = src[tid + i * 256];                           \
    }                                                                          \
    __syncthreads();                                                           \
    {                                                                          \
        const int jo = tid & 31;                                               \
        const int qb = (tid >> 5) * 4;                                         \
        float s[4] = {0.f, 0.f, 0.f, 0.f};                                     \
        for (int c4 = 0; c4 < 32; ++c4) {                                      \
            const float w0 = Woff[(c4 * 4 + 0) * 32 + jo];                     \
            const float w1 = Woff[(c4 * 4 + 1) * 32 + jo];                     \
            const float w2 = Woff[(c4 * 4 + 2) * 32 + jo];                     \
            const float w3 = Woff[(c4 * 4 + 3) * 32 + jo];                     \
            _Pragma("unroll")                                                  \
            for (int k = 0; k < 4; ++k) {                                      \
                const float4 q4 = *(const float4*)&q_tile[(qb + k) * 128 + c4 * 4]; \
                s[k] += q4.x * w0 + q4.y * w1 + q4.z * w2 + q4.w * w3;         \
            }                                                                  \
        }                                                                      \
        const int l = jo >> 4;                                                 \
        const int d = jo & 1;                                                  \
        const float scale = (d == 0) ? (l == 0 ? 256.f : 128.f)                \
                                     : (l == 0 ? 128.f : 64.f);                \
        const float bo = boff[jo];                                             \
        _Pragma("unroll")                                                      \
        for (int k = 0; k < 4; ++k) {                                          \
            const int row = r0 + qb + k;                                       \
            const float ql = qloc[row * 4 + l * 2 + d];                        \
            coords[(qb + k) * 32 + jo] = ql * scale + (s[k] + bo) - 0.5f;      \
        }                                                                      \
    }                                                                          \
    {                                                                          \
        const int ja = tid & 15;                                               \
        const int qb = (tid >> 4) * 2;                                         \
        float s[2] = {0.f, 0.f};                                               \
        for (int c4 = 0; c4 < 32; ++c4) {                                      \
            const float w0 = Wattn[(c4 * 4 + 0) * 16 + ja];                    \
            const float w1 = Wattn[(c4 * 4 + 1) * 16 + ja];                    \
            const float w2 = Wattn[(c4 * 4 + 2) * 16 + ja];                    \
            const float w3 = Wattn[(c4 * 4 + 3) * 16 + ja];                    \
            _Pragma("unroll")                                                  \
            for (int k = 0; k < 2; ++k) {                                      \
                const float4 q4 = *(const float4*)&q_tile[(qb + k) * 128 + c4 * 4]; \
                s[k] += q4.x * w0 + q4.y * w1 + q4.z * w2 + q4.w * w3;         \
            }                                                                  \
        }                                                                      \
        const float ba = battn[ja];                                            \
        _Pragma("unroll")                                                      \
        for (int k = 0; k < 2; ++k)                                            \
            aws[(qb + k) * 16 + ja] = s[k] + ba;                               \
    }                                                                          \
    __syncthreads();                                                           \
    if (tid < QB) {                                                            \
        float* a = &aws[tid * 16];                                             \
        float m = a[0];                                                        \
        _Pragma("unroll")                                                      \
        for (int j = 1; j < 16; ++j) m = fmaxf(m, a[j]);                       \
        float sum = 0.f;                                                       \
        _Pragma("unroll")                                                      \
        for (int j = 0; j < 16; ++j) {                                         \
            const float e = __expf(a[j] - m);                                  \
            a[j] = e;                                                          \
            sum += e;                                                          \
        }                                                                      \
        const float r = 1.f / sum;                                             \
        _Pragma("unroll")                                                      \
        for (int j = 0; j < 16; ++j) a[j] *= r;                                \
    }                                                                          \
    __syncthreads();                                                           \
    _Pragma("unroll")                                                          \
    for (int e = tid; e < QB * 16; e += 256) {                                 \
        const int q = e >> 4;                                                  \
        const int p = e & 15;                                                  \
        const int l = p >> 3;                                                  \
        const int H = l ? 64 : 128;                                            \
        const int W = l ? 128 : 256;                                           \
        const int S = l ? 32768 : 0;                                           \
        const float x   = coords[q * 32 + p * 2 + 0];                          \
        const float y   = coords[q * 32 + p * 2 + 1];                          \
        const float wgt = aws[q * 16 + p];                                     \
        const float xf = floorf(x), yf = floorf(y);                            \
        const float lx = x - xf, ly = y - yf;                                  \
        const int x0 = (int)xf, y0 = (int)yf;                                  \
        const int x1 = x0 + 1, y1 = y0 + 1;                                    \
        const float hx = 1.f - lx, hy = 1.f - ly;                              \
        float w00 = wgt * hx * hy;                                             \
        float w10 = wgt * lx * hy;                                             \
        float w01 = wgt * hx * ly;                                             \
        float w11 = wgt * lx * ly;                                             \
        if (x0 < 0 || x0 >= W) { w00 = 0.f; w01 = 0.f; }                       \
        if (x1 < 0 || x1 >= W) { w10 = 0.f; w11 = 0.f; }                       \
        if (y0 < 0 || y0 >= H) { w00 = 0.f; w10 = 0.f; }                       \
        if (y1 < 0 || y1 >= H) { w01 = 0.f; w11 = 0.f; }                       \
        const int cx0 = min(max(x0, 0), W - 1);                                \
        const int cx1 = min(max(x1, 0), W - 1);                                \
        const int cy0 = min(max(y0, 0), H - 1);                                \
        const int cy1 = min(max(y1, 0), H - 1);                                \
        int4 e0, e1;                                                           \
        e0.x = __float_as_int(w00); e0.y = __float_as_int(w01);                \
        e0.z = (S + cy0 * W + cx0) * 32; e0.w = (S + cy1 * W + cx0) * 32;      \
        e1.x = __float_as_int(w10); e1.y = __float_as_int(w11);                \
        e1.z = (S + cy0 * W + cx1) * 32; e1.w = (S + cy1 * W + cx1) * 32;      \
        tab[e * 2]     = e0;                                                   \
        tab[e * 2 + 1] = e1;                                                   \
    }                                                                          \
    __syncthreads();

// ---- gather, fp16 value path ----
__global__ __launch_bounds__(256, 4) void msda_gather_f16_kernel(
    const float* __restrict__ query,
    const h2x2*  __restrict__ value_h,
    const float* __restrict__ qloc,
    const float* __restrict__ Woff,
    const float* __restrict__ boff,
    const float* __restrict__ Wattn,
    const float* __restrict__ battn,
    float* __restrict__ acc_out)
{
    __shared__ __align__(16) char smem_u[QB * 128 * 4];
    __shared__ float coords[QB * 32];
    __shared__ float aws[QB * 16];
    MSDA_PROLOGUE

    {
        const int wv   = tid >> 6;
        const int lane = tid & 63;
        const int half = lane >> 5;
        const int cl   = lane & 31;
        const h2x2* vb = value_h + (size_t)(blockIdx.x >> 10) * (40960 * 32);
        float4* og = (float4*)acc_out;

        #pragma unroll 1
        for (int i = 0; i < 8; ++i) {
            const int q = wv * 8 + i;
            float ax = 0.f, ay = 0.f, az = 0.f, aw4 = 0.f;

            #pragma unroll 1
            for (int p0 = 0; p0 < 16; p0 += 8) {
                float wa[8], wb[8];
                int   oa[8], ob[8];
                #pragma unroll
                for (int pi = 0; pi < 8; ++pi) {
                    const int4 t = tab[((q * 16 + p0 + pi) << 1) + half];
                    wa[pi] = __int_as_float(t.x);
                    wb[pi] = __int_as_float(t.y);
                    oa[pi] = t.z + cl;
                    ob[pi] = t.w + cl;
                }
                h2x2 vA[8], vB[8];
                #pragma unroll
                for (int pi = 0; pi < 8; ++pi) {
                    vA[pi] = vb[oa[pi]];
                    vB[pi] = vb[ob[pi]];
                }
                #pragma unroll
                for (int pi = 0; pi < 8; ++pi) {
                    ax  += wa[pi] * __low2float(vA[pi].a);
                    ay  += wa[pi] * __high2float(vA[pi].a);
                    az  += wa[pi] * __low2float(vA[pi].b);
                    aw4 += wa[pi] * __high2float(vA[pi].b);
                    ax  += wb[pi] * __low2float(vB[pi].a);
                    ay  += wb[pi] * __high2float(vB[pi].a);
                    az  += wb[pi] * __low2float(vB[pi].b);
                    aw4 += wb[pi] * __high2float(vB[pi].b);
                }
            }
            ax  += __shfl_xor(ax, 32, 64);
            ay  += __shfl_xor(ay, 32, 64);
            az  += __shfl_xor(az, 32, 64);
            aw4 += __shfl_xor(aw4, 32, 64);
            if (half == 0)
                og[(size_t)(r0 + q) * 32 + cl] = make_float4(ax, ay, az, aw4);
        }
    }
}

// ---- gather, fp32 fallback (ws too small) ----
__global__ __launch_bounds__(256, 4) void msda_gather_f32_kernel(
    const float* __restrict__ query,
    const float* __restrict__ value,
    const float* __restrict__ qloc,
    const float* __restrict__ Woff,
    const float* __restrict__ boff,
    const float* __restrict__ Wattn,
    const float* __restrict__ battn,
    float* __restrict__ acc_out)
{
    __shared__ __align__(16) char smem_u[QB * 128 * 4];
    __shared__ float coords[QB * 32];
    __shared__ float aws[QB * 16];
    MSDA_PROLOGUE

    {
        const int wv   = tid >> 6;
        const int lane = tid & 63;
        const int half = lane >> 5;
        const int cl   = lane & 31;
        const float4* vb = (const float4*)value
                         + (size_t)(blockIdx.x >> 10) * (40960 * 32);
        float4* og = (float4*)acc_out;

        #pragma unroll 1
        for (int i = 0; i < 8; ++i) {
            const int q = wv * 8 + i;
            float ax = 0.f, ay = 0.f, az = 0.f, aw4 = 0.f;

            #pragma unroll 1
            for (int p0 = 0; p0 < 16; p0 += 8) {
                float wa[8], wb[8];
                int   oa[8], ob[8];
                #pragma unroll
                for (int pi = 0; pi < 8; ++pi) {
                    const int4 t = tab[((q * 16 + p0 + pi) << 1) + half];
                    wa[pi] = __int_as_float(t.x);
                    wb[pi] = __int_as_float(t.y);
                    oa[pi] = t.z + cl;
                    ob[pi] = t.w + cl;
                }
                float4 vA[8], vB[8];
                #pragma unroll
                for (int pi = 0; pi < 8; ++pi) {
                    vA[pi] = vb[oa[pi]];
                    vB[pi] = vb[ob[pi]];
                }
                #pragma unroll
                for (int pi = 0; pi < 8; ++pi) {
                    ax  += wa[pi] * vA[pi].x + wb[pi] * vB[pi].x;
                    ay  += wa[pi] * vA[pi].y + wb[pi] * vB[pi].y;
                    az  += wa[pi] * vA[pi].z + wb[pi] * vB[pi].z;
                    aw4 += wa[pi] * vA[pi].w + wb[pi] * vB[pi].w;
                }
            }
            ax  += __shfl_xor(ax, 32, 64);
            ay  += __shfl_xor(ay, 32, 64);
            az  += __shfl_xor(az, 32, 64);
            aw4 += __shfl_xor(aw4, 32, 64);
            if (half == 0)
                og[(size_t)(r0 + q) * 32 + cl] = make_float4(ax, ay, az, aw4);
        }
    }
}

// ---- MFMA fp16 output GEMM: out[128r x 128c] = acc @ Wout + bout, in-place ----
// A tile: acc rows cvt fp32->fp16, LDS [m][k] pad 136 (row stride 272 B: b128-
// aligned, 2-way bank alias = free). B tile: wTg (Wout^T fp16) coalesced copy,
// LDS [n][k] pad 136. mfma_f32_16x16x32_f16; C/D: col=lane&15, row=quad*4+reg.
__global__ __launch_bounds__(256, 2) void msda_out_gemm_mfma_kernel(
    const _Float16* __restrict__ wTg,
    const float* __restrict__ bout,
    float* __restrict__ out)
{
    __shared__ _Float16 aT[128 * 136];   // 34.0 KB
    __shared__ _Float16 wT[128 * 136];   // 34.0 KB
    const int tid = threadIdx.x;
    const int m0  = blockIdx.x * 128;

    // stage W^T (fp16, coalesced 16B chunks)
    #pragma unroll
    for (int i = 0; i < 8; ++i) {
        const int t  = tid + i * 256;    // 0..2047
        const int n  = t >> 4;
        const int k8 = t & 15;
        *(f16x8*)&wT[n * 136 + k8 * 8] = *(const f16x8*)&wTg[n * 128 + k8 * 8];
    }
    // stage A = acc rows (fp32 -> fp16)
    {
        const float4* src = (const float4*)out;
        #pragma unroll
        for (int i = 0; i < 16; ++i) {
            const int t  = tid + i * 256;   // 0..4095
            const int r  = t >> 5;
            const int c4 = t & 31;
            const float4 v = src[(size_t)(m0 + r) * 32 + c4];
            f16x4 h;
            h[0] = (_Float16)v.x; h[1] = (_Float16)v.y;
            h[2] = (_Float16)v.z; h[3] = (_Float16)v.w;
            *(f16x4*)&aT[r * 136 + c4 * 4] = h;
        }
    }
    __syncthreads();

    const int wv   = tid >> 6;     // wave 0..3 -> rows wv*32 .. wv*32+31
    const int lane = tid & 63;
    const int quad = lane >> 4;
    const int lr   = lane & 15;

    f32x4 acc_[2][8];
    #pragma unroll
    for (int mt = 0; mt < 2; ++mt)
        #pragma unroll
        for (int nt = 0; nt < 8; ++nt)
            acc_[mt][nt] = (f32x4){0.f, 0.f, 0.f, 0.f};

    #pragma unroll
    for (int k0 = 0; k0 < 128; k0 += 32) {
        const f16x8 a0 = *(const f16x8*)&aT[(wv * 32 +  0 + lr) * 136 + k0 + quad * 8];
        const f16x8 a1 = *(const f16x8*)&aT[(wv * 32 + 16 + lr) * 136 + k0 + quad * 8];
        #pragma unroll
        for (int nt = 0; nt < 8; ++nt) {
            const f16x8 b = *(const f16x8*)&wT[(nt * 16 + lr) * 136 + k0 + quad * 8];
            acc_[0][nt] = __builtin_amdgcn_mfma_f32_16x16x32_f16(a0, b, acc_[0][nt], 0, 0, 0);
            acc_[1][nt] = __builtin_amdgcn_mfma_f32_16x16x32_f16(a1, b, acc_[1][nt], 0, 0, 0);
        }
    }

    #pragma unroll
    for (int nt = 0; nt < 8; ++nt) {
        const float bb = bout[nt * 16 + lr];
        #pragma unroll
        for (int mt = 0; mt < 2; ++mt) {
            #pragma unroll
            for (int reg = 0; reg < 4; ++reg) {
                const int row = m0 + wv * 32 + mt * 16 + quad * 4 + reg;
                out[(size_t)row * 128 + nt * 16 + lr] = acc_[mt][nt][reg] + bb;
            }
        }
    }
}

// ---- fp32 output GEMM fallback (R6 version) ----
#define GR 128
__global__ __launch_bounds__(256, 2) void msda_out_gemm_f32_kernel(
    const float* __restrict__ Wout,
    const float* __restrict__ bout,
    float* __restrict__ out)
{
    __shared__ __align__(16) float a_tile[GR * 68];
    __shared__ __align__(16) float w_tile[64 * 128];
    const int tid  = threadIdx.x;
    const int r0   = blockIdx.x * GR;
    const int trow = tid >> 4;
    const int tcol = tid & 15;

    float4 o[8][2];
    #pragma unroll
    for (int k = 0; k < 8; ++k) {
        o[k][0] = make_float4(0.f, 0.f, 0.f, 0.f);
        o[k][1] = make_float4(0.f, 0.f, 0.f, 0.f);
    }

    #pragma unroll 1
    for (int h = 0; h < 2; ++h) {
        {
            const float4* src = (const float4*)out;
            #pragma unroll
            for (int i = 0; i < 8; ++i) {
                const int t  = tid + i * 256;
                const int r  = t >> 4;
                const int c4 = t & 15;
                const float4 v = src[(size_t)(r0 + r) * 32 + h * 16 + c4];
                *(float4*)&a_tile[r * 68 + c4 * 4] = v;
            }
            const float4* ws = (const float4*)Wout + (size_t)h * 64 * 32;
            float4* wd = (float4*)w_tile;
            #pragma unroll
            for (int i = 0; i < 8; ++i)
                wd[tid + i * 256] = ws[tid + i * 256];
        }
        __syncthreads();

        #pragma unroll 1
        for (int c4 = 0; c4 < 16; ++c4) {
            float4 a4[8];
            #pragma unroll
            for (int k = 0; k < 8; ++k)
                a4[k] = *(const float4*)&a_tile[(trow + 16 * k) * 68 + c4 * 4];
            #pragma unroll
            for (int j = 0; j < 4; ++j) {
                const int ci = c4 * 4 + j;
                const float4 w0 = *(const float4*)&w_tile[ci * 128 + tcol * 4];
                const float4 w1 = *(const float4*)&w_tile[ci * 128 + 64 + tcol * 4];
                #pragma unroll
                for (int k = 0; k < 8; ++k) {
                    const float a = (j == 0) ? a4[k].x : (j == 1) ? a4[k].y
                                  : (j == 2) ? a4[k].z : a4[k].w;
                    o[k][0].x += a * w0.x; o[k][0].y += a * w0.y;
                    o[k][0].z += a * w0.z; o[k][0].w += a * w0.w;
                    o[k][1].x += a * w1.x; o[k][1].y += a * w1.y;
                    o[k][1].z += a * w1.z; o[k][1].w += a * w1.w;
                }
            }
        }
        __syncthreads();
    }

    const float4 b0 = ((const float4*)bout)[tcol];
    const float4 b1 = ((const float4*)bout)[16 + tcol];
    float4* og = (float4*)out;
    #pragma unroll
    for (int k = 0; k < 8; ++k) {
        const size_t row = (size_t)(r0 + trow + 16 * k);
        float4 v0 = o[k][0], v1 = o[k][1];
        v0.x += b0.x; v0.y += b0.y; v0.z += b0.z; v0.w += b0.w;
        v1.x += b1.x; v1.y += b1.y; v1.z += b1.z; v1.w += b1.w;
        og[row * 32 + tcol]      = v0;
        og[row * 32 + 16 + tcol] = v1;
    }
}

extern "C" void kernel_launch(void* const* d_in, const int* in_sizes, int n_in,
                              void* d_out, int out_size, void* d_ws, size_t ws_size,
                              hipStream_t stream) {
    const float* query = (const float*)d_in[0];
    const float* value = (const float*)d_in[1];
    const float* qloc  = (const float*)d_in[2];
    const float* Woff  = (const float*)d_in[5];
    const float* boff  = (const float*)d_in[6];
    const float* Wattn = (const float*)d_in[7];
    const float* battn = (const float*)d_in[8];
    const float* Wout  = (const float*)d_in[9];
    const float* bout  = (const float*)d_in[10];
    float* out = (float*)d_out;

    const int n_val = 2 * 40960 * 128;                 // 10,485,760 floats
    const size_t f16_bytes = (size_t)n_val * 2;        // 20,971,520 B
    const size_t wT_bytes  = 128 * 128 * 2;            // 32,768 B

    if (ws_size >= f16_bytes + wT_bytes) {
        h2x2* val16 = (h2x2*)d_ws;
        _Float16* wTg = (_Float16*)((char*)d_ws + f16_bytes);
        const int n4 = n_val / 4;
        hipLaunchKernelGGL(cvt_value_f16_kernel, dim3((n4 + 255) / 256), dim3(256),
                           0, stream, (const float4*)value, val16, n4);
        hipLaunchKernelGGL(wout_transpose_kernel, dim3(1), dim3(256), 0, stream,
                           Wout, wTg);
        hipLaunchKernelGGL(msda_gather_f16_kernel, dim3(65536 / QB), dim3(256),
                           0, stream,
                           query, (const h2x2*)val16, qloc, Woff, boff, Wattn, battn, out);
        hipLaunchKernelGGL(msda_out_gemm_mfma_kernel, dim3(65536 / 128), dim3(256),
                           0, stream, (const _Float16*)wTg, bout, out);
    } else if (ws_size >= f16_bytes) {
        h2x2* val16 = (h2x2*)d_ws;
        const int n4 = n_val / 4;
        hipLaunchKernelGGL(cvt_value_f16_kernel, dim3((n4 + 255) / 256), dim3(256),
                           0, stream, (const float4*)value, val16, n4);
        hipLaunchKernelGGL(msda_gather_f16_kernel, dim3(65536 / QB), dim3(256),
                           0, stream,
                           query, (const h2x2*)val16, qloc, Woff, boff, Wattn, battn, out);
        hipLaunchKernelGGL(msda_out_gemm_f32_kernel, dim3(65536 / GR), dim3(256),
                           0, stream, Wout, bout, out);
    } else {
        hipLaunchKernelGGL(msda_gather_f32_kernel, dim3(65536 / QB), dim3(256),
                           0, stream,
                           query, value, qloc, Woff, boff, Wattn, battn, out);
        hipLaunchKernelGGL(msda_out_gemm_f32_kernel, dim3(65536 / GR), dim3(256),
                           0, stream, Wout, bout, out);
    }
}